// Round 2
// baseline (221.163 us; speedup 1.0000x reference)
//
#include <hip/hip_runtime.h>
#include <hip/hip_bf16.h>
#include <math.h>

// Problem constants (reference: B,T,D,H = 64,2048,256,5)
constexpr int BB    = 64;
constexpr int TT    = 2048;
constexpr int DD    = 256;
constexpr int HH    = 5;
constexpr int SEG   = 16;            // segments per batch row
constexpr int TSEG  = TT / SEG;      // 128 timesteps per block
constexpr int TC    = 32;            // chunk timesteps staged in LDS
constexpr int STRIDE= 260;           // LDS row stride (floats): conflict-free col reads

// fast tanh: 1 - 2/(e^{2x}+1), exp via v_exp, rcp via v_rcp. |err| ~1e-6.
__device__ __forceinline__ float ftanh(float x) {
    float e = __expf(2.0f * x);
    return 1.0f - 2.0f * __builtin_amdgcn_rcpf(e + 1.0f);
}

// One block = (batch row b, segment seg). Online softmax over its 128 timesteps,
// x staged chunk-by-chunk in LDS so x_temp is read from HBM exactly once.
__global__ __launch_bounds__(256, 4)
void seg_kernel(const float* __restrict__ x_temp,
                const float* __restrict__ x_fea,
                const int* __restrict__ mask,            // harness passes bool as int32
                const float* __restrict__ W_temp,        // (D,H) row-major
                const float* __restrict__ b_temp,        // (H,)
                const float* __restrict__ W_fea,         // (1,H)
                const float* __restrict__ b_fea,         // (H,)
                const float* __restrict__ uw,            // (H,H) row-major
                float* __restrict__ part)                // (B*SEG, 2+D)
{
    __shared__ float ldsx[TC * STRIDE];
    __shared__ float ldsi[TC];

    const int tid  = threadIdx.x;
    const int lane = tid & 63;
    const int wave = tid >> 6;
    const int half = lane >> 5;      // which timestep of the pair
    const int l32  = lane & 31;      // 32 lanes cover D=256, 8 floats each
    const int blk  = blockIdx.x;
    const int b    = blk / SEG;
    const int seg  = blk % SEG;
    const int t0   = seg * TSEG;

    // Preload per-lane W_temp rows (d = l32*8 .. +7), 40 regs, reused all timesteps.
    const int dbase = l32 * 8;
    float wv[8][HH];
#pragma unroll
    for (int e = 0; e < 8; ++e)
#pragma unroll
        for (int h = 0; h < HH; ++h)
            wv[e][h] = W_temp[(dbase + e) * HH + h];

    float wfea[HH], bfea[HH], btmp[HH], uwr[HH];
#pragma unroll
    for (int h = 0; h < HH; ++h) {
        wfea[h] = W_fea[h];
        bfea[h] = b_fea[h];
        btmp[h] = b_temp[h];
        float s = 0.f;
#pragma unroll
        for (int h2 = 0; h2 < HH; ++h2) s += uw[h * HH + h2];
        uwr[h] = s;   // sum(hadamard@uw+b, -1) = hadamard . uwr + const (const cancels in softmax)
    }

    float m = -INFINITY, l = 0.f, acc = 0.f;   // online-softmax state; acc for d = tid
    const size_t rowbase = (size_t)b * TT;

    for (int c = 0; c < TSEG / TC; ++c) {
        const int tbase = t0 + c * TC;

        // ---- compute phase: each wave handles 4 pairs of timesteps ----
#pragma unroll
        for (int p = 0; p < 4; ++p) {
            const int tl = wave * 8 + p * 2 + half;       // 0..31 within chunk
            const int t  = tbase + tl;
            const float4* xr = (const float4*)(x_temp + (rowbase + t) * (size_t)DD);
            float4 a0 = xr[l32 * 2 + 0];
            float4 a1 = xr[l32 * 2 + 1];

            // stage to LDS for the accumulation phase
            float* row = &ldsx[tl * STRIDE + dbase];
            *(float4*)(row)     = a0;
            *(float4*)(row + 4) = a1;

            // partial dots vs 5 W columns
            float ph[HH];
#pragma unroll
            for (int h = 0; h < HH; ++h)
                ph[h] = a0.x * wv[0][h] + a0.y * wv[1][h] + a0.z * wv[2][h] + a0.w * wv[3][h]
                      + a1.x * wv[4][h] + a1.y * wv[5][h] + a1.z * wv[6][h] + a1.w * wv[7][h];

            // half-wave butterfly (masks <=16 stay within each 32-lane half)
#pragma unroll
            for (int off = 16; off >= 1; off >>= 1)
#pragma unroll
                for (int h = 0; h < HH; ++h)
                    ph[h] += __shfl_xor(ph[h], off);

            const float xf = x_fea[rowbase + t];
            float inter = 0.f;
#pragma unroll
            for (int h = 0; h < HH; ++h) {
                float tt = ftanh(ph[h] + btmp[h]);
                float tf = ftanh(xf * wfea[h] + bfea[h]);
                inter += tt * tf * uwr[h];
            }
            if (l32 == 0) ldsi[tl] = inter;
        }
        __syncthreads();

        // ---- accumulation phase: thread tid owns column d = tid ----
        float cmax = -INFINITY;
#pragma unroll
        for (int t = 0; t < TC; ++t) cmax = fmaxf(cmax, ldsi[t]);
        const float newm = fmaxf(m, cmax);
        const float sc = __expf(m - newm);     // exp(-inf)=0 on first chunk
        acc *= sc; l *= sc; m = newm;

        const int* mrow = mask + rowbase + tbase;
#pragma unroll 8
        for (int t = 0; t < TC; ++t) {
            float w = mrow[t] ? __expf(ldsi[t] - m) : 0.f;
            l += w;
            acc = fmaf(w, ldsx[t * STRIDE + tid], acc);
        }
        __syncthreads();   // before next chunk overwrites ldsx/ldsi
    }

    float* pb = part + (size_t)blk * (DD + 2);
    if (tid == 0) { pb[0] = m; pb[1] = l; }
    pb[2 + tid] = acc;
}

// Merge the SEG partials per batch row.
__global__ void combine_kernel(const float* __restrict__ part, float* __restrict__ out)
{
    const int b = blockIdx.x;
    const int d = threadIdx.x;
    float M = -INFINITY;
    for (int s = 0; s < SEG; ++s)
        M = fmaxf(M, part[(size_t)(b * SEG + s) * (DD + 2)]);
    float denom = 0.f, num = 0.f;
    for (int s = 0; s < SEG; ++s) {
        const float* p = part + (size_t)(b * SEG + s) * (DD + 2);
        float sc = __expf(p[0] - M);
        denom += sc * p[1];
        num   += sc * p[2 + d];
    }
    out[(size_t)b * DD + d] = num / denom;
}

extern "C" void kernel_launch(void* const* d_in, const int* in_sizes, int n_in,
                              void* d_out, int out_size, void* d_ws, size_t ws_size,
                              hipStream_t stream) {
    const float* x_temp = (const float*)d_in[0];
    const float* x_fea  = (const float*)d_in[1];
    const int*   mask   = (const int*)d_in[2];     // bool -> int32 per harness convention
    const float* W_temp = (const float*)d_in[3];
    const float* b_temp = (const float*)d_in[4];
    const float* W_fea  = (const float*)d_in[5];
    const float* b_fea  = (const float*)d_in[6];
    // d_in[7] = b : constant shift across T, cancels in softmax — unused.
    const float* uw     = (const float*)d_in[8];

    float* part = (float*)d_ws;                 // (B*SEG) x (2+D) floats ~ 1.03 MB
    float* out  = (float*)d_out;

    seg_kernel<<<BB * SEG, 256, 0, stream>>>(x_temp, x_fea, mask, W_temp,
                                             b_temp, W_fea, b_fea, uw, part);
    combine_kernel<<<BB, DD, 0, stream>>>(part, out);
}